// Round 13
// baseline (82.916 us; speedup 1.0000x reference)
//
#include <hip/hip_runtime.h>

#define BH  64
#define SEQ 4096
#define DH  64
#define NCHUNK 32
#define CROWS  (SEQ / NCHUNK)   // 128 rows per chunk
#define NT     (CROWS / 32)     // 4 tiles of 32 rows

typedef __attribute__((ext_vector_type(8))) short bf16x8v;  // 8 bf16 (4 VGPR)
typedef __attribute__((ext_vector_type(4))) float f32x4v;   // MFMA acc

// fp32 -> bf16, round-to-nearest-even
__device__ __forceinline__ short f2bf(float x) {
  unsigned u = __float_as_uint(x);
  return (short)((u + 0x7FFFu + ((u >> 16) & 1u)) >> 16);
}

// async global->LDS, 16B per lane; LDS dest = wave-uniform base + lane*16
__device__ __forceinline__ void gload_lds16(const float* g, float* l) {
  __builtin_amdgcn_global_load_lds(
      (const __attribute__((address_space(1))) void*)g,
      (__attribute__((address_space(3))) void*)l, 16, 0, 0);
}

// ---------------------------------------------------------------------------
// Kernel 1: partial kv = k^T v over a 128-row chunk. ONE WAVE per block.
// The wave owns the full 64x64 output (4x4 MFMA 16x16 tiles, 64 acc VGPR).
// ZERO barriers: LDS ring-2 buffers are wave-private, so counted vmcnt alone
// orders staging vs compute; every wave advances independently (the fix for
// three rounds of barrier-lockstep stall at ~53 us with idle pipes).
// Staging via global_load_lds with SOURCE pre-swizzle (rule #21):
//   element [row][col] lives at lds[row*64 + (col ^ ((row>>3)<<4))]
// -> fragment ds_read_b32 banks become 2-way (free) instead of 4-way.
// Fragment & C/D layouts HW-verified in rounds 10-12.
// ---------------------------------------------------------------------------
__global__ __launch_bounds__(64) void kv_partial_kernel(
    const float* __restrict__ k, const float* __restrict__ v,
    float* __restrict__ partial) {
  const int l  = threadIdx.x;
  const int bh = blockIdx.x >> 5;             // / NCHUNK
  const int chunk = blockIdx.x & (NCHUNK - 1);
  const int lg = l >> 4;     // 0..3
  const int ln = l & 15;     // 0..15

  const float* kb = k + (size_t)bh * SEQ * DH + (size_t)chunk * CROWS * DH;
  const float* vb = v + (size_t)bh * SEQ * DH + (size_t)chunk * CROWS * DH;

  // floats: k bufs [0,4096) | v bufs [4096,8192)  (2 x 8 KB per tensor)
  __shared__ float smem[8192];

  f32x4v acc[4][4];
#pragma unroll
  for (int m = 0; m < 4; ++m)
#pragma unroll
    for (int n = 0; n < 4; ++n) acc[m][n] = (f32x4v){0.f, 0.f, 0.f, 0.f};

  // stage tile tt (32 rows x 64 f32 = 2048 floats per tensor) into buf tt&1.
  // dest F = i*256 + l*4 -> row = i*4+lg, col_lds = ln*4;
  // source col = col_lds ^ ((row>>3)<<4) = (ln*4) ^ (((i>>1)&3)<<4).
  auto STAGE = [&](int tt) {
    const int buf = tt & 1;
    const float* kt = kb + (size_t)tt * 2048;
    const float* vt = vb + (size_t)tt * 2048;
    float* kd = smem + buf * 2048;
    float* vd = smem + 4096 + buf * 2048;
#pragma unroll
    for (int i = 0; i < 8; ++i) {
      const int so = (i * 4 + lg) * 64 + ((ln * 4) ^ (((i >> 1) & 3) << 4));
      gload_lds16(kt + so, kd + i * 256);
      gload_lds16(vt + so, vd + i * 256);
    }
  };

  auto COMPUTE = [&](int tt) {
    const float* ks = smem + (tt & 1) * 2048;
    const float* vs = smem + 4096 + (tt & 1) * 2048;
    bf16x8v a[4], b[4];
#pragma unroll
    for (int c = 0; c < 4; ++c) {
#pragma unroll
      for (int j = 0; j < 8; ++j) {
        // element [lg*8+j][c*16+ln], row>>3 == lg -> XOR lg<<4
        const int addr = (lg * 8 + j) * 64 + ((c * 16 + ln) ^ (lg << 4));
        a[c][j] = f2bf(ks[addr]);
        b[c][j] = f2bf(vs[addr]);
      }
    }
#pragma unroll
    for (int m = 0; m < 4; ++m)
#pragma unroll
      for (int n = 0; n < 4; ++n)
        acc[m][n] = __builtin_amdgcn_mfma_f32_16x16x32_bf16(
            a[m], b[n], acc[m][n], 0, 0, 0);
  };

  // 2-ahead pipeline, counted vmcnt (16 insts per STAGE), no barriers.
  STAGE(0);
  STAGE(1);
#pragma unroll
  for (int tt = 0; tt < NT; ++tt) {
    if (tt + 1 < NT) {
      asm volatile("s_waitcnt vmcnt(16)" ::: "memory");  // tile tt landed
    } else {
      asm volatile("s_waitcnt vmcnt(0)" ::: "memory");
    }
    __builtin_amdgcn_sched_barrier(0);
    COMPUTE(tt);
    __builtin_amdgcn_sched_barrier(0);   // keep stage AFTER this tile's reads
    if (tt + 2 < NT) STAGE(tt + 2);
  }

  // C/D layout (HW-verified): col = lane&15, row = (lane>>4)*4 + reg
  float* pb = partial + (size_t)blockIdx.x * (DH * DH);
#pragma unroll
  for (int m = 0; m < 4; ++m)
#pragma unroll
    for (int n = 0; n < 4; ++n)
#pragma unroll
      for (int r = 0; r < 4; ++r)
        pb[(m * 16 + lg * 4 + r) * 64 + n * 16 + ln] = acc[m][n][r];
}

// ---------------------------------------------------------------------------
// Kernel 2: reduce partials -> kvf [BH][64*64]. 256 blocks x 256 threads
// covers 65536 float4 slots.
// ---------------------------------------------------------------------------
__global__ __launch_bounds__(256) void kv_reduce_kernel(
    const float* __restrict__ partial, float* __restrict__ kvf) {
  const int gid = blockIdx.x * 256 + threadIdx.x;
  const int bh = gid >> 10;
  const int idx = gid & 1023;
  float4 s = {0.f, 0.f, 0.f, 0.f};
  for (int c = 0; c < NCHUNK; ++c) {
    const float4* p = (const float4*)(partial + ((size_t)bh * NCHUNK + c) * (DH * DH));
    float4 x = p[idx];
    s.x += x.x; s.y += x.y; s.z += x.z; s.w += x.w;
  }
  ((float4*)kvf)[gid] = s;
}

// ---------------------------------------------------------------------------
// Kernel 3: out = q @ kv. Block = 64 q-rows. Thread = 1 row x 16 cols.
// Entire q row hoisted to registers up front; kv in LDS, broadcast reads.
// At its BW roofline (~18 us) -- unchanged.
// ---------------------------------------------------------------------------
__global__ __launch_bounds__(256) void out_kernel(
    const float* __restrict__ q, const float* __restrict__ kvf,
    float* __restrict__ out) {
  const int t = threadIdx.x;
  const int bh = blockIdx.x >> 6;
  const int rb = blockIdx.x & 63;
  const int row = rb * 64 + (t >> 2);
  const int c0 = (t & 3) * 16;

  __shared__ float kv_lds[64 * 64];

  const float4* gkv4 = (const float4*)(kvf + (size_t)bh * (DH * DH));
  float4* kv4 = (float4*)kv_lds;
#pragma unroll
  for (int j = 0; j < 4; ++j) kv4[t + j * 256] = gkv4[t + j * 256];

  const float* qrow = q + (size_t)bh * SEQ * DH + (size_t)row * DH;
  float4 qv[16];
#pragma unroll
  for (int i = 0; i < 16; ++i) qv[i] = *(const float4*)&qrow[i * 4];

  __syncthreads();

  float acc[16];
#pragma unroll
  for (int j = 0; j < 16; ++j) acc[j] = 0.f;

#pragma unroll
  for (int dc = 0; dc < 16; ++dc) {
    float qs[4] = {qv[dc].x, qv[dc].y, qv[dc].z, qv[dc].w};
#pragma unroll
    for (int dd = 0; dd < 4; ++dd) {
      const float* kr = &kv_lds[(dc * 4 + dd) * 64 + c0];
      float4 k0 = *(const float4*)&kr[0];
      float4 k1 = *(const float4*)&kr[4];
      float4 k2 = *(const float4*)&kr[8];
      float4 k3 = *(const float4*)&kr[12];
      const float qsv = qs[dd];
      acc[0]  += qsv * k0.x; acc[1]  += qsv * k0.y;
      acc[2]  += qsv * k0.z; acc[3]  += qsv * k0.w;
      acc[4]  += qsv * k1.x; acc[5]  += qsv * k1.y;
      acc[6]  += qsv * k1.z; acc[7]  += qsv * k1.w;
      acc[8]  += qsv * k2.x; acc[9]  += qsv * k2.y;
      acc[10] += qsv * k2.z; acc[11] += qsv * k2.w;
      acc[12] += qsv * k3.x; acc[13] += qsv * k3.y;
      acc[14] += qsv * k3.z; acc[15] += qsv * k3.w;
    }
  }

  float* ob = out + (size_t)bh * SEQ * DH + (size_t)row * DH + c0;
#pragma unroll
  for (int j = 0; j < 4; ++j) {
    float4 w = {acc[4 * j + 0], acc[4 * j + 1], acc[4 * j + 2], acc[4 * j + 3]};
    *(float4*)&ob[4 * j] = w;
  }
}

// ---------------------------------------------------------------------------
extern "C" void kernel_launch(void* const* d_in, const int* in_sizes, int n_in,
                              void* d_out, int out_size, void* d_ws, size_t ws_size,
                              hipStream_t stream) {
  const float* q = (const float*)d_in[0];
  const float* k = (const float*)d_in[1];
  const float* v = (const float*)d_in[2];
  float* out = (float*)d_out;

  float* kvf = (float*)d_ws;                      // [BH][64*64] = 1 MB
  float* partial = kvf + (size_t)BH * DH * DH;    // [BH*NCHUNK][64*64] = 32 MB

  hipLaunchKernelGGL(kv_partial_kernel, dim3(BH * NCHUNK), dim3(64), 0, stream,
                     k, v, partial);
  hipLaunchKernelGGL(kv_reduce_kernel, dim3(256), dim3(256), 0, stream,
                     partial, kvf);
  hipLaunchKernelGGL(out_kernel, dim3(BH * 64), dim3(256), 0, stream,
                     q, kvf, out);
}